// Round 7
// baseline (24403.305 us; speedup 1.0000x reference)
//
#include <hip/hip_runtime.h>
#include <math.h>

typedef float f32x2 __attribute__((ext_vector_type(2)));
typedef float f32x4 __attribute__((ext_vector_type(4)));

#define LOG2E 1.4426950408889634f

__device__ __forceinline__ float rcp_fast(float x)  { return __builtin_amdgcn_rcpf(x); }
__device__ __forceinline__ float exp2_fast(float x) { return __builtin_amdgcn_exp2f(x); }
__device__ __forceinline__ float exp_fast(float x)  { return exp2_fast(x * LOG2E); }

// tanh(x) = 1 - 2/(e^{2x}+1). Saturates correctly at +-1.
__device__ __forceinline__ float tanh_fast(float x) {
    float e = exp2_fast(x * (2.0f * LOG2E));
    return 1.0f - 2.0f * rcp_fast(e + 1.0f);
}
// 0.5*(tanh(5x)+1) == sigmoid(10x)
__device__ __forceinline__ float step_fast(float x) {
    return rcp_fast(1.0f + exp2_fast(x * (-10.0f * LOG2E)));
}
__device__ __forceinline__ float sinh_fast(float x) {
    float e = exp2_fast(x * LOG2E);
    return 0.5f * e - 0.5f * rcp_fast(e);
}

__device__ __forceinline__ f32x2 mk2(float a, float b) { f32x2 r; r.x = a; r.y = b; return r; }

// acc = fma(a, b, acc) packed — one VALU instruction.
__device__ __forceinline__ void pk_fma(f32x2& acc, f32x2 a, f32x2 b) {
    asm("v_pk_fma_f32 %0, %1, %2, %0" : "+v"(acc) : "v"(a), "v"(b));
}

#define DPP_ADD(x, ctrl, rmask)                                                         \
    x += __builtin_bit_cast(float, __builtin_amdgcn_update_dpp(                         \
             0, __builtin_bit_cast(int, x), ctrl, rmask, 0xf, true))

// Full 64-lane sum via DPP; total lands in lane 63 -> readlane -> uniform.
// ALL-LANE, uniform result — proven in R2/R3/R5.
__device__ __forceinline__ float wave_sum64(float x) {
    DPP_ADD(x, 0x111, 0xf);   // row_shr:1
    DPP_ADD(x, 0x112, 0xf);   // row_shr:2
    DPP_ADD(x, 0x114, 0xf);   // row_shr:4
    DPP_ADD(x, 0x118, 0xf);   // row_shr:8
    DPP_ADD(x, 0x142, 0xa);   // row_bcast:15
    DPP_ADD(x, 0x143, 0xc);   // row_bcast:31
    return __builtin_bit_cast(float, __builtin_amdgcn_readlane(__builtin_bit_cast(int, x), 63));
}

#define CHUNK 1024

// ---------------------------------------------------------------------------
// RK4 scan: 256 threads = 4 waves on the CU's 4 SIMDs.
// KEY CHANGE vs R6: amdgpu_waves_per_eu(1,1) pins the register allocator's
// occupancy TARGET to 1 wave/EU -> VGPR pressure limit 512 -> no spilling of
// the ~80 weight registers. (R5/R6's VGPR_Count=64 == 512/8 showed the RA was
// targeting 8 waves/EU occupancy and spilling w2r to scratch every rhs;
// __launch_bounds__'s 2nd arg is only a correctness floor, not the target.)
// Only one block ever runs (sequential scan), so occupancy 1 is exactly right.
// ---------------------------------------------------------------------------
extern "C" __global__ void
__attribute__((amdgpu_flat_work_group_size(256, 256), amdgpu_waves_per_eu(1, 1)))
scan_kernel(const float* __restrict__ x,
            const float* __restrict__ precp,
            const float* __restrict__ temp,
            const float* __restrict__ lday,
            const float* __restrict__ W1, const float* __restrict__ b1,
            const float* __restrict__ W2, const float* __restrict__ b2,
            const float* __restrict__ W3, const float* __restrict__ b3,
            float* __restrict__ sol, int T)
{
    const int tid  = threadIdx.x;     // 0..255
    const int lane = tid & 63;
    const int w    = tid >> 6;        // wave 0..3
    const int half = lane >> 5;       // K-half 0/1 (half-wave)
    const int j    = (w << 5) + (lane & 31);   // layer2/3 column 0..127

    __shared__ __align__(16) float h1w[4][128];      // per-wave private
    __shared__ __align__(16) float red5[2][5][4];    // [parity][output][wave]
    __shared__ float pr_s[CHUNK + 1], tm_s[CHUNK + 1], ld_s[CHUNK + 1];

    // ---- layer-1 weights: columns lane and lane+64 ----
    float w1a[4], w1b[4];
#pragma unroll
    for (int i = 0; i < 4; ++i) {
        w1a[i] = W1[i * 128 + lane];
        w1b[i] = W1[i * 128 + lane + 64];
    }
    float b1a = b1[lane], b1b = b1[lane + 64];

    // ---- layer-2 weights: own K-half of column j ----
    f32x2 w2r[32];
#pragma unroll
    for (int m = 0; m < 32; ++m) {
        const int k0 = (half << 6) + 2 * m;
        w2r[m] = mk2(W2[k0 * 128 + j], W2[(k0 + 1) * 128 + j]);
    }
    float b2j = b2[j];

    // ---- layer-3 weights: masked to 0 on half=1 lanes (avoid double count)
    float w3r[5];
#pragma unroll
    for (int c = 0; c < 5; ++c) w3r[c] = (half == 0) ? W3[j * 5 + c] : 0.0f;
    const float b30 = b3[0], b31 = b3[1], b32 = b3[2], b33 = b3[3], b34 = b3[4];

    float S0 = x[0], S1 = x[1];
    if (tid == 0) { sol[0] = S0; sol[1] = S1; }

    auto rhs = [&](int par, float z0, float z1, float pr, float tm, float ld,
                   float& d0, float& d1) {
        // uniform transcendentals independent of the MLP — off the critical chain
        const float sS0 = step_fast(z0);
        const float sS1 = step_fast(z1);
        const float sNT = step_fast(-tm);

        // layer 1: this wave computes ALL 128 columns (2 per lane) privately
        float a0 = b1a, a1 = b1b;
        a0 = fmaf(z0, w1a[0], a0);  a1 = fmaf(z0, w1b[0], a1);
        a0 = fmaf(z1, w1a[1], a0);  a1 = fmaf(z1, w1b[1], a1);
        a0 = fmaf(pr, w1a[2], a0);  a1 = fmaf(pr, w1b[2], a1);
        a0 = fmaf(tm, w1a[3], a0);  a1 = fmaf(tm, w1b[3], a1);
        h1w[w][lane]      = tanh_fast(a0);
        h1w[w][lane + 64] = tanh_fast(a1);
        asm volatile("" ::: "memory");     // compiler memory fence: LDS writes stay above reads
        __builtin_amdgcn_wave_barrier();   // scheduling fence (same-wave DS pipe is in-order)

        // layer 2: own K-half; every 32-lane phase reads ONE address (broadcast)
        const float* hb = &h1w[w][half << 6];
        f32x2 acc0 = mk2(0.f, 0.f), acc1 = mk2(0.f, 0.f);
#pragma unroll
        for (int m = 0; m < 16; ++m) {
            f32x4 hv = *reinterpret_cast<const f32x4*>(hb + 4 * m);
            pk_fma(acc0, hv.xy, w2r[2 * m]);
            pk_fma(acc1, hv.zw, w2r[2 * m + 1]);
        }
        float s = (acc0.x + acc0.y) + (acc1.x + acc1.y);
        s += __shfl_xor(s, 32);            // combine K-halves (lane ^ 32)
        const float h2 = tanh_fast(s + b2j);

        // layer 3: half0-masked partials -> 5 all-lane wave sums (uniform)
        const float q0 = wave_sum64(h2 * w3r[0]);
        const float q1 = wave_sum64(h2 * w3r[1]);
        const float q2 = wave_sum64(h2 * w3r[2]);
        const float q3 = wave_sum64(h2 * w3r[3]);
        const float q4 = wave_sum64(h2 * w3r[4]);
        if (lane == 0) {
            red5[par][0][w] = q0; red5[par][1][w] = q1; red5[par][2][w] = q2;
            red5[par][3][w] = q3; red5[par][4][w] = q4;
        }
        __syncthreads();                                   // the ONE barrier

        f32x4 v0 = *reinterpret_cast<const f32x4*>(&red5[par][0][0]);
        f32x4 v1 = *reinterpret_cast<const f32x4*>(&red5[par][1][0]);
        f32x4 v2 = *reinterpret_cast<const f32x4*>(&red5[par][2][0]);
        f32x4 v3 = *reinterpret_cast<const f32x4*>(&red5[par][3][0]);
        f32x4 v4 = *reinterpret_cast<const f32x4*>(&red5[par][4][0]);
        const float o0 = (v0.x + v0.y) + (v0.z + v0.w) + b30;
        const float o1 = (v1.x + v1.y) + (v1.z + v1.w) + b31;
        const float o2 = (v2.x + v2.y) + (v2.z + v2.w) + b32;
        const float o3 = (v3.x + v3.y) + (v3.z + v3.w) + b33;
        const float o4 = (v4.x + v4.y) + (v4.z + v4.w) + b34;

        // epilogue (uniform)
        const float melt = sS0 * sinh_fast(o2);            // relu(step)=step
        d0 = fmaxf(sinh_fast(o3) * sNT, 0.0f) - melt;
        d1 = fmaxf(sinh_fast(o4), 0.0f) + melt
             - sS1 * fmaf(ld, exp_fast(o0), exp_fast(o1));
    };

    // rolling register prefetch (B of step n == A of step n+1)
    float pB = precp[0], tB = temp[0], lB = lday[0];

    for (int cbase = 0; cbase < T - 1; cbase += CHUNK) {
        for (int i = tid; i <= CHUNK; i += 256) {
            int g = cbase + i;
            if (g < T) {
                pr_s[i] = precp[g];
                tm_s[i] = temp[g];
                ld_s[i] = lday[g];
            }
        }
        __syncthreads();

        const int len = min(T - 1 - cbase, CHUNK);
#pragma unroll 1
        for (int l = 0; l < len; ++l) {
            // ---- PIN weights as loop-carried opaque register values ----
            // With waves_per_eu(1,1) the RA has budget 512 and these pins
            // guarantee residency instead of forcing spill round-trips.
#pragma unroll
            for (int m = 0; m < 32; ++m) asm volatile("" : "+v"(w2r[m]));
#pragma unroll
            for (int i = 0; i < 4; ++i)  asm volatile("" : "+v"(w1a[i]), "+v"(w1b[i]));
#pragma unroll
            for (int c = 0; c < 5; ++c)  asm volatile("" : "+v"(w3r[c]));
            asm volatile("" : "+v"(b1a), "+v"(b1b), "+v"(b2j));

            const float pA = pB, tA = tB, lA = lB;
            pB = pr_s[l + 1];
            tB = tm_s[l + 1];
            lB = ld_s[l + 1];
            const float pM = 0.5f * (pA + pB);
            const float tM = 0.5f * (tA + tB);
            const float lM = 0.5f * (lA + lB);

            float k10, k11, k20, k21, k30, k31, k40, k41;
            rhs(0, S0, S1, pA, tA, lA, k10, k11);                              // h = 1
            rhs(1, fmaf(0.5f, k10, S0), fmaf(0.5f, k11, S1), pM, tM, lM, k20, k21);
            rhs(0, fmaf(0.5f, k20, S0), fmaf(0.5f, k21, S1), pM, tM, lM, k30, k31);
            rhs(1, k30 + S0,            k31 + S1,            pB, tB, lB, k40, k41);

            const float c = 1.0f / 6.0f;
            S0 = S0 + c * (k10 + 2.0f * (k20 + k30) + k40);
            S1 = S1 + c * (k11 + 2.0f * (k21 + k31) + k41);
            if (tid == 0) {
                const int n = cbase + l;
                sol[2 * (n + 1)]     = S0;
                sol[2 * (n + 1) + 1] = S1;
            }
        }
        __syncthreads();   // protect series LDS re-stage vs stragglers
    }
}

// ---------------------------------------------------------------------------
// Output: y[t] = exp(mlp([sol0,sol1,x2,x3])[1]) — fully parallel, tiny.
// ---------------------------------------------------------------------------
extern "C" __global__ void __launch_bounds__(128)
out_kernel(const float* __restrict__ x,
           const float* __restrict__ sol,
           const float* __restrict__ W1, const float* __restrict__ b1,
           const float* __restrict__ W2, const float* __restrict__ b2,
           const float* __restrict__ W3, const float* __restrict__ b3,
           float* __restrict__ y, int T)
{
    const int j    = threadIdx.x;
    const int lane = j & 63;
    const int wv   = j >> 6;

    __shared__ __align__(16) float h1s[128];
    __shared__ float red[2];

    float w1c[4], w2c[128];
#pragma unroll
    for (int i = 0; i < 4; ++i)   w1c[i] = W1[i * 128 + j];
    const float b1j = b1[j];
#pragma unroll
    for (int i = 0; i < 128; ++i) w2c[i] = W2[i * 128 + j];
    const float b2j = b2[j];
    const float w31 = W3[j * 5 + 1];
    const float b31 = b3[1];

#pragma unroll 1
    for (int r = blockIdx.x; r < T; r += gridDim.x) {
        const float z0 = sol[2 * r], z1 = sol[2 * r + 1];
        const float z2 = x[4 * r + 2], z3 = x[4 * r + 3];
        float a = b1j;
        a = fmaf(z0, w1c[0], a);
        a = fmaf(z1, w1c[1], a);
        a = fmaf(z2, w1c[2], a);
        a = fmaf(z3, w1c[3], a);
        h1s[j] = tanh_fast(a);
        __syncthreads();
        float acc0 = 0.f, acc1 = 0.f, acc2 = 0.f, acc3 = 0.f;
#pragma unroll
        for (int i = 0; i < 128; i += 4) {
            const float4 hv = *reinterpret_cast<const float4*>(&h1s[i]);
            acc0 = fmaf(hv.x, w2c[i + 0], acc0);
            acc1 = fmaf(hv.y, w2c[i + 1], acc1);
            acc2 = fmaf(hv.z, w2c[i + 2], acc2);
            acc3 = fmaf(hv.w, w2c[i + 3], acc3);
        }
        const float h2 = tanh_fast(((acc0 + acc1) + (acc2 + acc3)) + b2j);
        float p = h2 * w31;
#pragma unroll
        for (int off = 32; off >= 1; off >>= 1)
            p += __shfl_xor(p, off);
        if (lane == 0) red[wv] = p;
        __syncthreads();
        if (j == 0) y[r] = exp_fast(red[0] + red[1] + b31);
        __syncthreads();
    }
}

// ---------------------------------------------------------------------------
extern "C" void kernel_launch(void* const* d_in, const int* in_sizes, int n_in,
                              void* d_out, int out_size, void* d_ws, size_t ws_size,
                              hipStream_t stream)
{
    const float* x      = (const float*)d_in[0];
    // d_in[1] = t_eval = arange(T) -> h == 1.0
    // d_in[2] = t_grid = arange(T)
    const float* precp  = (const float*)d_in[3];
    const float* temp   = (const float*)d_in[4];
    const float* lday   = (const float*)d_in[5];
    const float* W1     = (const float*)d_in[6];
    const float* b1     = (const float*)d_in[7];
    const float* W2     = (const float*)d_in[8];
    const float* b2     = (const float*)d_in[9];
    const float* W3     = (const float*)d_in[10];
    const float* b3     = (const float*)d_in[11];
    float*       y      = (float*)d_out;
    float*       sol    = (float*)d_ws;      // T*2 floats
    const int    T      = in_sizes[1];

    hipLaunchKernelGGL(scan_kernel, dim3(1), dim3(256), 0, stream,
                       x, precp, temp, lday,
                       W1, b1, W2, b2, W3, b3, sol, T);
    hipLaunchKernelGGL(out_kernel, dim3(256), dim3(128), 0, stream,
                       x, sol, W1, b1, W2, b2, W3, b3, y, T);
}

// Round 8
// 18593.602 us; speedup vs baseline: 1.3125x; 1.3125x over previous
//
#include <hip/hip_runtime.h>
#include <math.h>

typedef float f32x2 __attribute__((ext_vector_type(2)));
typedef float f32x4 __attribute__((ext_vector_type(4)));

#define LOG2E 1.4426950408889634f

__device__ __forceinline__ float rcp_fast(float x)  { return __builtin_amdgcn_rcpf(x); }
__device__ __forceinline__ float exp2_fast(float x) { return __builtin_amdgcn_exp2f(x); }
__device__ __forceinline__ float exp_fast(float x)  { return exp2_fast(x * LOG2E); }

// tanh(x) = 1 - 2/(e^{2x}+1). Saturates correctly at +-1.
__device__ __forceinline__ float tanh_fast(float x) {
    float e = exp2_fast(x * (2.0f * LOG2E));
    return 1.0f - 2.0f * rcp_fast(e + 1.0f);
}
// 0.5*(tanh(5x)+1) == sigmoid(10x)
__device__ __forceinline__ float step_fast(float x) {
    return rcp_fast(1.0f + exp2_fast(x * (-10.0f * LOG2E)));
}
__device__ __forceinline__ float sinh_fast(float x) {
    float e = exp2_fast(x * LOG2E);
    return 0.5f * e - 0.5f * rcp_fast(e);
}

__device__ __forceinline__ float readlane_f(float x, int l) {
    return __builtin_bit_cast(float,
        __builtin_amdgcn_readlane(__builtin_bit_cast(int, x), l));
}

#define DPP_ADD(x, ctrl, rmask)                                                         \
    x += __builtin_bit_cast(float, __builtin_amdgcn_update_dpp(                         \
             0, __builtin_bit_cast(int, x), ctrl, rmask, 0xf, true))

// Full 64-lane sum via DPP; total lands in lane 63 -> readlane -> uniform.
// ALL-LANE, uniform result — proven R2/R3/R5.
__device__ __forceinline__ float wave_sum64(float x) {
    DPP_ADD(x, 0x111, 0xf);   // row_shr:1
    DPP_ADD(x, 0x112, 0xf);   // row_shr:2
    DPP_ADD(x, 0x114, 0xf);   // row_shr:4
    DPP_ADD(x, 0x118, 0xf);   // row_shr:8
    DPP_ADD(x, 0x142, 0xa);   // row_bcast:15
    DPP_ADD(x, 0x143, 0xc);   // row_bcast:31
    return readlane_f(x, 63);
}

#define CHUNK 1024

// ---------------------------------------------------------------------------
// RK4 scan: 256 threads = 4 waves.
// KEY CHANGE vs R7: layer 2 no longer touches LDS. R3/R5/R7 all pinned at
// ~24 ms regardless of spills/conflicts/barriers -> shared bottleneck was the
// per-CU DS pipe (64x ds_read_b128 + red5 + h1 writes per rhs). Now:
//   - K-split across waves: wave w owns K-rows [32w,32w+32); it computes
//     those 32 h1 columns itself in registers (layer 1, lanes 0-31).
//   - Layer 2 broadcast via v_readlane (VALU) feeding v_fmac with SGPR
//     operand: 32 readlane + 64 fmac per wave, ZERO DS-pipe traffic.
//   - Only remaining LDS/rhs: 2 ds_write_b32 + 8 ds_read_b32 per wave
//     (cross-wave partial combine, conflict-free part[w][col] layout,
//     parity double-buffered), ONE __syncthreads.
// ---------------------------------------------------------------------------
extern "C" __global__ void
__attribute__((amdgpu_flat_work_group_size(256, 256), amdgpu_waves_per_eu(1, 1)))
scan_kernel(const float* __restrict__ x,
            const float* __restrict__ precp,
            const float* __restrict__ temp,
            const float* __restrict__ lday,
            const float* __restrict__ W1, const float* __restrict__ b1,
            const float* __restrict__ W2, const float* __restrict__ b2,
            const float* __restrict__ W3, const float* __restrict__ b3,
            float* __restrict__ sol, int T)
{
    const int tid  = threadIdx.x;      // 0..255
    const int lane = tid & 63;
    const int w    = tid >> 6;         // wave 0..3 (owns K-rows 32w..32w+31)
    const int kcol = (w << 5) + (lane & 31);   // layer-1 column this lane computes

    __shared__ float part[2][4][128];                  // [parity][wave][col]
    __shared__ float pr_s[CHUNK + 1], tm_s[CHUNK + 1], ld_s[CHUNK + 1];

    // ---- layer-1 weights for column kcol (the K-row this wave broadcasts) ----
    float w1q[4];
#pragma unroll
    for (int i = 0; i < 4; ++i) w1q[i] = W1[i * 128 + kcol];
    float b1q = b1[kcol];

    // ---- layer-2 weights: rows [32w,32w+32) of columns lane and lane+64 ----
    float w2a[32], w2b[32];
#pragma unroll
    for (int k = 0; k < 32; ++k) {
        const int row = (w << 5) + k;
        w2a[k] = W2[row * 128 + lane];
        w2b[k] = W2[row * 128 + lane + 64];
    }
    float b2a = b2[lane], b2b = b2[lane + 64];

    // ---- layer-3 weights: columns lane and lane+64 ----
    float w3a[5], w3b[5];
#pragma unroll
    for (int c = 0; c < 5; ++c) {
        w3a[c] = W3[lane * 5 + c];
        w3b[c] = W3[(lane + 64) * 5 + c];
    }
    const float b30 = b3[0], b31 = b3[1], b32 = b3[2], b33 = b3[3], b34 = b3[4];

    float S0 = x[0], S1 = x[1];
    if (tid == 0) { sol[0] = S0; sol[1] = S1; }

    auto rhs = [&](int par, float z0, float z1, float pr, float tm, float ld,
                   float& d0, float& d1) {
        // uniform transcendentals independent of the MLP — off the critical chain
        const float sS0 = step_fast(z0);
        const float sS1 = step_fast(z1);
        const float sNT = step_fast(-tm);

        // layer 1: this wave's 32 K-rows (lanes 32-63 duplicate lanes 0-31)
        float a = b1q;
        a = fmaf(z0, w1q[0], a);
        a = fmaf(z1, w1q[1], a);
        a = fmaf(pr, w1q[2], a);
        a = fmaf(tm, w1q[3], a);
        const float h = tanh_fast(a);

        // layer 2: readlane broadcast (VALU, no LDS). Lane owns cols lane, lane+64.
        float aa0 = 0.f, aa1 = 0.f, ab0 = 0.f, ab1 = 0.f;
#pragma unroll
        for (int k = 0; k < 32; k += 2) {
            const float hk0 = readlane_f(h, k);
            const float hk1 = readlane_f(h, k + 1);
            aa0 = fmaf(hk0, w2a[k],     aa0);
            ab0 = fmaf(hk0, w2b[k],     ab0);
            aa1 = fmaf(hk1, w2a[k + 1], aa1);
            ab1 = fmaf(hk1, w2b[k + 1], ab1);
        }
        // cross-wave combine: the ONLY LDS in the rhs
        part[par][w][lane]      = aa0 + aa1;
        part[par][w][lane + 64] = ab0 + ab1;
        __syncthreads();                                   // the ONE barrier

        const float sa = ((part[par][0][lane] + part[par][1][lane]) +
                          (part[par][2][lane] + part[par][3][lane])) + b2a;
        const float sb = ((part[par][0][lane + 64] + part[par][1][lane + 64]) +
                          (part[par][2][lane + 64] + part[par][3][lane + 64])) + b2b;
        const float h2a = tanh_fast(sa);
        const float h2b = tanh_fast(sb);

        // layer 3: per-lane partials over 2 columns -> 5 wave sums (uniform)
        const float o0 = wave_sum64(fmaf(h2b, w3b[0], h2a * w3a[0])) + b30;
        const float o1 = wave_sum64(fmaf(h2b, w3b[1], h2a * w3a[1])) + b31;
        const float o2 = wave_sum64(fmaf(h2b, w3b[2], h2a * w3a[2])) + b32;
        const float o3 = wave_sum64(fmaf(h2b, w3b[3], h2a * w3a[3])) + b33;
        const float o4 = wave_sum64(fmaf(h2b, w3b[4], h2a * w3a[4])) + b34;

        // epilogue (uniform)
        const float melt = sS0 * sinh_fast(o2);            // relu(step)=step
        d0 = fmaxf(sinh_fast(o3) * sNT, 0.0f) - melt;
        d1 = fmaxf(sinh_fast(o4), 0.0f) + melt
             - sS1 * fmaf(ld, exp_fast(o0), exp_fast(o1));
    };

    // rolling register prefetch (B of step n == A of step n+1)
    float pB = precp[0], tB = temp[0], lB = lday[0];

    for (int cbase = 0; cbase < T - 1; cbase += CHUNK) {
        for (int i = tid; i <= CHUNK; i += 256) {
            int g = cbase + i;
            if (g < T) {
                pr_s[i] = precp[g];
                tm_s[i] = temp[g];
                ld_s[i] = lday[g];
            }
        }
        __syncthreads();

        const int len = min(T - 1 - cbase, CHUNK);
#pragma unroll 1
        for (int l = 0; l < len; ++l) {
            // ---- PIN weights as loop-carried opaque register values ----
            // (waves_per_eu(1,1) gives the RA budget 512, so these enforce
            //  residency instead of forcing spill round-trips)
#pragma unroll
            for (int k = 0; k < 32; ++k) asm volatile("" : "+v"(w2a[k]), "+v"(w2b[k]));
#pragma unroll
            for (int i = 0; i < 4; ++i)  asm volatile("" : "+v"(w1q[i]));
#pragma unroll
            for (int c = 0; c < 5; ++c)  asm volatile("" : "+v"(w3a[c]), "+v"(w3b[c]));
            asm volatile("" : "+v"(b1q), "+v"(b2a), "+v"(b2b));

            const float pA = pB, tA = tB, lA = lB;
            pB = pr_s[l + 1];
            tB = tm_s[l + 1];
            lB = ld_s[l + 1];
            const float pM = 0.5f * (pA + pB);
            const float tM = 0.5f * (tA + tB);
            const float lM = 0.5f * (lA + lB);

            float k10, k11, k20, k21, k30, k31, k40, k41;
            rhs(0, S0, S1, pA, tA, lA, k10, k11);                              // h = 1
            rhs(1, fmaf(0.5f, k10, S0), fmaf(0.5f, k11, S1), pM, tM, lM, k20, k21);
            rhs(0, fmaf(0.5f, k20, S0), fmaf(0.5f, k21, S1), pM, tM, lM, k30, k31);
            rhs(1, k30 + S0,            k31 + S1,            pB, tB, lB, k40, k41);

            const float c = 1.0f / 6.0f;
            S0 = S0 + c * (k10 + 2.0f * (k20 + k30) + k40);
            S1 = S1 + c * (k11 + 2.0f * (k21 + k31) + k41);
            if (tid == 0) {
                const int n = cbase + l;
                sol[2 * (n + 1)]     = S0;
                sol[2 * (n + 1) + 1] = S1;
            }
        }
        __syncthreads();   // protect series LDS re-stage vs stragglers
    }
}

// ---------------------------------------------------------------------------
// Output: y[t] = exp(mlp([sol0,sol1,x2,x3])[1]) — fully parallel, tiny.
// ---------------------------------------------------------------------------
extern "C" __global__ void __launch_bounds__(128)
out_kernel(const float* __restrict__ x,
           const float* __restrict__ sol,
           const float* __restrict__ W1, const float* __restrict__ b1,
           const float* __restrict__ W2, const float* __restrict__ b2,
           const float* __restrict__ W3, const float* __restrict__ b3,
           float* __restrict__ y, int T)
{
    const int j    = threadIdx.x;
    const int lane = j & 63;
    const int wv   = j >> 6;

    __shared__ __align__(16) float h1s[128];
    __shared__ float red[2];

    float w1c[4], w2c[128];
#pragma unroll
    for (int i = 0; i < 4; ++i)   w1c[i] = W1[i * 128 + j];
    const float b1j = b1[j];
#pragma unroll
    for (int i = 0; i < 128; ++i) w2c[i] = W2[i * 128 + j];
    const float b2j = b2[j];
    const float w31 = W3[j * 5 + 1];
    const float b31 = b3[1];

#pragma unroll 1
    for (int r = blockIdx.x; r < T; r += gridDim.x) {
        const float z0 = sol[2 * r], z1 = sol[2 * r + 1];
        const float z2 = x[4 * r + 2], z3 = x[4 * r + 3];
        float a = b1j;
        a = fmaf(z0, w1c[0], a);
        a = fmaf(z1, w1c[1], a);
        a = fmaf(z2, w1c[2], a);
        a = fmaf(z3, w1c[3], a);
        h1s[j] = tanh_fast(a);
        __syncthreads();
        float acc0 = 0.f, acc1 = 0.f, acc2 = 0.f, acc3 = 0.f;
#pragma unroll
        for (int i = 0; i < 128; i += 4) {
            const float4 hv = *reinterpret_cast<const float4*>(&h1s[i]);
            acc0 = fmaf(hv.x, w2c[i + 0], acc0);
            acc1 = fmaf(hv.y, w2c[i + 1], acc1);
            acc2 = fmaf(hv.z, w2c[i + 2], acc2);
            acc3 = fmaf(hv.w, w2c[i + 3], acc3);
        }
        const float h2 = tanh_fast(((acc0 + acc1) + (acc2 + acc3)) + b2j);
        float p = h2 * w31;
#pragma unroll
        for (int off = 32; off >= 1; off >>= 1)
            p += __shfl_xor(p, off);
        if (lane == 0) red[wv] = p;
        __syncthreads();
        if (j == 0) y[r] = exp_fast(red[0] + red[1] + b31);
        __syncthreads();
    }
}

// ---------------------------------------------------------------------------
extern "C" void kernel_launch(void* const* d_in, const int* in_sizes, int n_in,
                              void* d_out, int out_size, void* d_ws, size_t ws_size,
                              hipStream_t stream)
{
    const float* x      = (const float*)d_in[0];
    // d_in[1] = t_eval = arange(T) -> h == 1.0
    // d_in[2] = t_grid = arange(T)
    const float* precp  = (const float*)d_in[3];
    const float* temp   = (const float*)d_in[4];
    const float* lday   = (const float*)d_in[5];
    const float* W1     = (const float*)d_in[6];
    const float* b1     = (const float*)d_in[7];
    const float* W2     = (const float*)d_in[8];
    const float* b2     = (const float*)d_in[9];
    const float* W3     = (const float*)d_in[10];
    const float* b3     = (const float*)d_in[11];
    float*       y      = (float*)d_out;
    float*       sol    = (float*)d_ws;      // T*2 floats
    const int    T      = in_sizes[1];

    hipLaunchKernelGGL(scan_kernel, dim3(1), dim3(256), 0, stream,
                       x, precp, temp, lday,
                       W1, b1, W2, b2, W3, b3, sol, T);
    hipLaunchKernelGGL(out_kernel, dim3(256), dim3(128), 0, stream,
                       x, sol, W1, b1, W2, b2, W3, b3, y, T);
}

// Round 9
// 18457.994 us; speedup vs baseline: 1.3221x; 1.0073x over previous
//
#include <hip/hip_runtime.h>
#include <math.h>

typedef float f32x2 __attribute__((ext_vector_type(2)));
typedef float f32x4 __attribute__((ext_vector_type(4)));

#define LOG2E 1.4426950408889634f

__device__ __forceinline__ float rcp_fast(float x)  { return __builtin_amdgcn_rcpf(x); }
__device__ __forceinline__ float exp2_fast(float x) { return __builtin_amdgcn_exp2f(x); }
__device__ __forceinline__ float exp_fast(float x)  { return exp2_fast(x * LOG2E); }

// tanh(x) = 1 - 2/(e^{2x}+1). Saturates correctly at +-1.
__device__ __forceinline__ float tanh_fast(float x) {
    float e = exp2_fast(x * (2.0f * LOG2E));
    return 1.0f - 2.0f * rcp_fast(e + 1.0f);
}
// 0.5*(tanh(5x)+1) == sigmoid(10x)
__device__ __forceinline__ float step_fast(float x) {
    return rcp_fast(1.0f + exp2_fast(x * (-10.0f * LOG2E)));
}
__device__ __forceinline__ float sinh_fast(float x) {
    float e = exp2_fast(x * LOG2E);
    return 0.5f * e - 0.5f * rcp_fast(e);
}

__device__ __forceinline__ float readlane_f(float x, int l) {
    return __builtin_bit_cast(float,
        __builtin_amdgcn_readlane(__builtin_bit_cast(int, x), l));
}

#define DPP_ADD(x, ctrl, rmask)                                                         \
    x += __builtin_bit_cast(float, __builtin_amdgcn_update_dpp(                         \
             0, __builtin_bit_cast(int, x), ctrl, rmask, 0xf, true))

// Full 64-lane sum via DPP; total lands in lane 63 -> readlane -> uniform.
__device__ __forceinline__ float wave_sum64(float x) {
    DPP_ADD(x, 0x111, 0xf);   // row_shr:1
    DPP_ADD(x, 0x112, 0xf);   // row_shr:2
    DPP_ADD(x, 0x114, 0xf);   // row_shr:4
    DPP_ADD(x, 0x118, 0xf);   // row_shr:8
    DPP_ADD(x, 0x142, 0xa);   // row_bcast:15
    DPP_ADD(x, 0x143, 0xc);   // row_bcast:31
    return readlane_f(x, 63);
}

// Barrier that waits ONLY on LDS ops (lgkmcnt), not global stores (vmcnt).
// __syncthreads() emits s_waitcnt vmcnt(0) lgkmcnt(0) + s_barrier; the vmcnt
// drain forces every wave to wait for wave-0's outstanding sol[] global store
// each step. LDS producer->consumer ordering only needs lgkmcnt.
__device__ __forceinline__ void barrier_lgkm() {
    asm volatile("s_waitcnt lgkmcnt(0)" ::: "memory");
    __builtin_amdgcn_s_barrier();
    asm volatile("" ::: "memory");
}

#define CHUNK 1024

// ---------------------------------------------------------------------------
// RK4 scan: 256 threads = 4 waves (R8 structure).
// R9 micro-cuts: (1) lgkm-only barrier in rhs (no vmcnt drain of sol store);
// (2) layer-2 chain depth 16->8 via 8 accumulators; (3) readlanes hoisted
// into a static register array (amortize SGPR-write hazard).
// ---------------------------------------------------------------------------
extern "C" __global__ void
__attribute__((amdgpu_flat_work_group_size(256, 256), amdgpu_waves_per_eu(1, 1)))
scan_kernel(const float* __restrict__ x,
            const float* __restrict__ precp,
            const float* __restrict__ temp,
            const float* __restrict__ lday,
            const float* __restrict__ W1, const float* __restrict__ b1,
            const float* __restrict__ W2, const float* __restrict__ b2,
            const float* __restrict__ W3, const float* __restrict__ b3,
            float* __restrict__ sol, int T)
{
    const int tid  = threadIdx.x;      // 0..255
    const int lane = tid & 63;
    const int w    = tid >> 6;         // wave 0..3 (owns K-rows 32w..32w+31)
    const int kcol = (w << 5) + (lane & 31);   // layer-1 column this lane computes

    __shared__ float part[2][4][128];                  // [parity][wave][col]
    __shared__ float pr_s[CHUNK + 1], tm_s[CHUNK + 1], ld_s[CHUNK + 1];

    // ---- layer-1 weights for column kcol ----
    float w1q[4];
#pragma unroll
    for (int i = 0; i < 4; ++i) w1q[i] = W1[i * 128 + kcol];
    float b1q = b1[kcol];

    // ---- layer-2 weights: rows [32w,32w+32) of columns lane and lane+64 ----
    float w2a[32], w2b[32];
#pragma unroll
    for (int k = 0; k < 32; ++k) {
        const int row = (w << 5) + k;
        w2a[k] = W2[row * 128 + lane];
        w2b[k] = W2[row * 128 + lane + 64];
    }
    float b2a = b2[lane], b2b = b2[lane + 64];

    // ---- layer-3 weights: columns lane and lane+64 ----
    float w3a[5], w3b[5];
#pragma unroll
    for (int c = 0; c < 5; ++c) {
        w3a[c] = W3[lane * 5 + c];
        w3b[c] = W3[(lane + 64) * 5 + c];
    }
    const float b30 = b3[0], b31 = b3[1], b32 = b3[2], b33 = b3[3], b34 = b3[4];

    float S0 = x[0], S1 = x[1];
    if (tid == 0) { sol[0] = S0; sol[1] = S1; }

    auto rhs = [&](int par, float z0, float z1, float pr, float tm, float ld,
                   float& d0, float& d1) {
        // uniform transcendentals independent of the MLP — off the critical chain
        const float sS0 = step_fast(z0);
        const float sS1 = step_fast(z1);
        const float sNT = step_fast(-tm);

        // layer 1: this wave's 32 K-rows (lanes 32-63 duplicate lanes 0-31)
        float a = b1q;
        a = fmaf(z0, w1q[0], a);
        a = fmaf(z1, w1q[1], a);
        a = fmaf(pr, w1q[2], a);
        a = fmaf(tm, w1q[3], a);
        const float h = tanh_fast(a);

        // hoist all 32 broadcasts first (back-to-back readlanes amortize the
        // SGPR-write->VALU-read hazard); static indices -> registers
        float hk[32];
#pragma unroll
        for (int k = 0; k < 32; ++k) hk[k] = readlane_f(h, k);

        // layer 2: 8 accumulators -> dependency chains of 8 (was 16)
        float aa0 = 0.f, aa1 = 0.f, aa2 = 0.f, aa3 = 0.f;
        float ab0 = 0.f, ab1 = 0.f, ab2 = 0.f, ab3 = 0.f;
#pragma unroll
        for (int k = 0; k < 32; k += 4) {
            aa0 = fmaf(hk[k],     w2a[k],     aa0);
            ab0 = fmaf(hk[k],     w2b[k],     ab0);
            aa1 = fmaf(hk[k + 1], w2a[k + 1], aa1);
            ab1 = fmaf(hk[k + 1], w2b[k + 1], ab1);
            aa2 = fmaf(hk[k + 2], w2a[k + 2], aa2);
            ab2 = fmaf(hk[k + 2], w2b[k + 2], ab2);
            aa3 = fmaf(hk[k + 3], w2a[k + 3], aa3);
            ab3 = fmaf(hk[k + 3], w2b[k + 3], ab3);
        }
        // cross-wave combine: the ONLY LDS in the rhs
        part[par][w][lane]      = (aa0 + aa1) + (aa2 + aa3);
        part[par][w][lane + 64] = (ab0 + ab1) + (ab2 + ab3);
        barrier_lgkm();                                    // the ONE barrier (lgkm only)

        const float sa = ((part[par][0][lane] + part[par][1][lane]) +
                          (part[par][2][lane] + part[par][3][lane])) + b2a;
        const float sb = ((part[par][0][lane + 64] + part[par][1][lane + 64]) +
                          (part[par][2][lane + 64] + part[par][3][lane + 64])) + b2b;
        const float h2a = tanh_fast(sa);
        const float h2b = tanh_fast(sb);

        // layer 3: per-lane partials over 2 columns -> 5 wave sums (uniform)
        const float o0 = wave_sum64(fmaf(h2b, w3b[0], h2a * w3a[0])) + b30;
        const float o1 = wave_sum64(fmaf(h2b, w3b[1], h2a * w3a[1])) + b31;
        const float o2 = wave_sum64(fmaf(h2b, w3b[2], h2a * w3a[2])) + b32;
        const float o3 = wave_sum64(fmaf(h2b, w3b[3], h2a * w3a[3])) + b33;
        const float o4 = wave_sum64(fmaf(h2b, w3b[4], h2a * w3a[4])) + b34;

        // epilogue (uniform)
        const float melt = sS0 * sinh_fast(o2);            // relu(step)=step
        d0 = fmaxf(sinh_fast(o3) * sNT, 0.0f) - melt;
        d1 = fmaxf(sinh_fast(o4), 0.0f) + melt
             - sS1 * fmaf(ld, exp_fast(o0), exp_fast(o1));
    };

    // rolling register prefetch (B of step n == A of step n+1)
    float pB = precp[0], tB = temp[0], lB = lday[0];

    for (int cbase = 0; cbase < T - 1; cbase += CHUNK) {
        for (int i = tid; i <= CHUNK; i += 256) {
            int g = cbase + i;
            if (g < T) {
                pr_s[i] = precp[g];
                tm_s[i] = temp[g];
                ld_s[i] = lday[g];
            }
        }
        __syncthreads();

        const int len = min(T - 1 - cbase, CHUNK);
#pragma unroll 1
        for (int l = 0; l < len; ++l) {
            // ---- PIN weights as loop-carried opaque register values ----
#pragma unroll
            for (int k = 0; k < 32; ++k) asm volatile("" : "+v"(w2a[k]), "+v"(w2b[k]));
#pragma unroll
            for (int i = 0; i < 4; ++i)  asm volatile("" : "+v"(w1q[i]));
#pragma unroll
            for (int c = 0; c < 5; ++c)  asm volatile("" : "+v"(w3a[c]), "+v"(w3b[c]));
            asm volatile("" : "+v"(b1q), "+v"(b2a), "+v"(b2b));

            const float pA = pB, tA = tB, lA = lB;
            pB = pr_s[l + 1];
            tB = tm_s[l + 1];
            lB = ld_s[l + 1];
            const float pM = 0.5f * (pA + pB);
            const float tM = 0.5f * (tA + tB);
            const float lM = 0.5f * (lA + lB);

            float k10, k11, k20, k21, k30, k31, k40, k41;
            rhs(0, S0, S1, pA, tA, lA, k10, k11);                              // h = 1
            rhs(1, fmaf(0.5f, k10, S0), fmaf(0.5f, k11, S1), pM, tM, lM, k20, k21);
            rhs(0, fmaf(0.5f, k20, S0), fmaf(0.5f, k21, S1), pM, tM, lM, k30, k31);
            rhs(1, k30 + S0,            k31 + S1,            pB, tB, lB, k40, k41);

            const float c = 1.0f / 6.0f;
            S0 = S0 + c * (k10 + 2.0f * (k20 + k30) + k40);
            S1 = S1 + c * (k11 + 2.0f * (k21 + k31) + k41);
            if (tid == 0) {
                const int n = cbase + l;
                sol[2 * (n + 1)]     = S0;
                sol[2 * (n + 1) + 1] = S1;
            }
        }
        __syncthreads();   // protect series LDS re-stage vs stragglers
    }
}

// ---------------------------------------------------------------------------
// Output: y[t] = exp(mlp([sol0,sol1,x2,x3])[1]) — fully parallel, tiny.
// ---------------------------------------------------------------------------
extern "C" __global__ void __launch_bounds__(128)
out_kernel(const float* __restrict__ x,
           const float* __restrict__ sol,
           const float* __restrict__ W1, const float* __restrict__ b1,
           const float* __restrict__ W2, const float* __restrict__ b2,
           const float* __restrict__ W3, const float* __restrict__ b3,
           float* __restrict__ y, int T)
{
    const int j    = threadIdx.x;
    const int lane = j & 63;
    const int wv   = j >> 6;

    __shared__ __align__(16) float h1s[128];
    __shared__ float red[2];

    float w1c[4], w2c[128];
#pragma unroll
    for (int i = 0; i < 4; ++i)   w1c[i] = W1[i * 128 + j];
    const float b1j = b1[j];
#pragma unroll
    for (int i = 0; i < 128; ++i) w2c[i] = W2[i * 128 + j];
    const float b2j = b2[j];
    const float w31 = W3[j * 5 + 1];
    const float b31 = b3[1];

#pragma unroll 1
    for (int r = blockIdx.x; r < T; r += gridDim.x) {
        const float z0 = sol[2 * r], z1 = sol[2 * r + 1];
        const float z2 = x[4 * r + 2], z3 = x[4 * r + 3];
        float a = b1j;
        a = fmaf(z0, w1c[0], a);
        a = fmaf(z1, w1c[1], a);
        a = fmaf(z2, w1c[2], a);
        a = fmaf(z3, w1c[3], a);
        h1s[j] = tanh_fast(a);
        __syncthreads();
        float acc0 = 0.f, acc1 = 0.f, acc2 = 0.f, acc3 = 0.f;
#pragma unroll
        for (int i = 0; i < 128; i += 4) {
            const float4 hv = *reinterpret_cast<const float4*>(&h1s[i]);
            acc0 = fmaf(hv.x, w2c[i + 0], acc0);
            acc1 = fmaf(hv.y, w2c[i + 1], acc1);
            acc2 = fmaf(hv.z, w2c[i + 2], acc2);
            acc3 = fmaf(hv.w, w2c[i + 3], acc3);
        }
        const float h2 = tanh_fast(((acc0 + acc1) + (acc2 + acc3)) + b2j);
        float p = h2 * w31;
#pragma unroll
        for (int off = 32; off >= 1; off >>= 1)
            p += __shfl_xor(p, off);
        if (lane == 0) red[wv] = p;
        __syncthreads();
        if (j == 0) y[r] = exp_fast(red[0] + red[1] + b31);
        __syncthreads();
    }
}

// ---------------------------------------------------------------------------
extern "C" void kernel_launch(void* const* d_in, const int* in_sizes, int n_in,
                              void* d_out, int out_size, void* d_ws, size_t ws_size,
                              hipStream_t stream)
{
    const float* x      = (const float*)d_in[0];
    // d_in[1] = t_eval = arange(T) -> h == 1.0
    // d_in[2] = t_grid = arange(T)
    const float* precp  = (const float*)d_in[3];
    const float* temp   = (const float*)d_in[4];
    const float* lday   = (const float*)d_in[5];
    const float* W1     = (const float*)d_in[6];
    const float* b1     = (const float*)d_in[7];
    const float* W2     = (const float*)d_in[8];
    const float* b2     = (const float*)d_in[9];
    const float* W3     = (const float*)d_in[10];
    const float* b3     = (const float*)d_in[11];
    float*       y      = (float*)d_out;
    float*       sol    = (float*)d_ws;      // T*2 floats
    const int    T      = in_sizes[1];

    hipLaunchKernelGGL(scan_kernel, dim3(1), dim3(256), 0, stream,
                       x, precp, temp, lday,
                       W1, b1, W2, b2, W3, b3, sol, T);
    hipLaunchKernelGGL(out_kernel, dim3(256), dim3(128), 0, stream,
                       x, sol, W1, b1, W2, b2, W3, b3, y, T);
}

// Round 10
// 18117.392 us; speedup vs baseline: 1.3470x; 1.0188x over previous
//
#include <hip/hip_runtime.h>
#include <math.h>

typedef float f32x2 __attribute__((ext_vector_type(2)));
typedef float f32x4 __attribute__((ext_vector_type(4)));

#define LOG2E 1.4426950408889634f

__device__ __forceinline__ float rcp_fast(float x)  { return __builtin_amdgcn_rcpf(x); }
__device__ __forceinline__ float exp2_fast(float x) { return __builtin_amdgcn_exp2f(x); }
__device__ __forceinline__ float exp_fast(float x)  { return exp2_fast(x * LOG2E); }

// tanh(x) = 1 - 2/(e^{2x}+1). Saturates correctly at +-1.
__device__ __forceinline__ float tanh_fast(float x) {
    float e = exp2_fast(x * (2.0f * LOG2E));
    return 1.0f - 2.0f * rcp_fast(e + 1.0f);
}
// 0.5*(tanh(5x)+1) == sigmoid(10x)
__device__ __forceinline__ float step_fast(float x) {
    return rcp_fast(1.0f + exp2_fast(x * (-10.0f * LOG2E)));
}
__device__ __forceinline__ float sinh_fast(float x) {
    float e = exp2_fast(x * LOG2E);
    return 0.5f * e - 0.5f * rcp_fast(e);
}

__device__ __forceinline__ float readlane_f(float x, int l) {
    return __builtin_bit_cast(float,
        __builtin_amdgcn_readlane(__builtin_bit_cast(int, x), l));
}

#define DPP_ADD(x, ctrl, rmask)                                                         \
    x += __builtin_bit_cast(float, __builtin_amdgcn_update_dpp(                         \
             0, __builtin_bit_cast(int, x), ctrl, rmask, 0xf, true))

// Full 64-lane sum via DPP; total lands in lane 63 -> readlane -> uniform.
__device__ __forceinline__ float wave_sum64(float x) {
    DPP_ADD(x, 0x111, 0xf);   // row_shr:1
    DPP_ADD(x, 0x112, 0xf);   // row_shr:2
    DPP_ADD(x, 0x114, 0xf);   // row_shr:4
    DPP_ADD(x, 0x118, 0xf);   // row_shr:8
    DPP_ADD(x, 0x142, 0xa);   // row_bcast:15
    DPP_ADD(x, 0x143, 0xc);   // row_bcast:31
    return readlane_f(x, 63);
}

// Barrier that waits ONLY on LDS ops (lgkmcnt), not global stores (vmcnt).
__device__ __forceinline__ void barrier_lgkm() {
    asm volatile("s_waitcnt lgkmcnt(0)" ::: "memory");
    __builtin_amdgcn_s_barrier();
    asm volatile("" ::: "memory");
}

#define CHUNK 1024

// ---------------------------------------------------------------------------
// RK4 scan: 256 threads = 4 waves (R8/R9 structure).
// R10: REMOVED all per-iteration pin asms — amdgpu_waves_per_eu(1,1) is the
// sole residency mechanism (RA budget 512, no occupancy motive to spill).
// The 81 volatile pins executed every iteration were the last unisolated
// codegen unknown; this round measures them. Also reverted the hk[] hoist
// (R9-neutral) to R8's direct interleaved readlanes.
// ---------------------------------------------------------------------------
extern "C" __global__ void
__attribute__((amdgpu_flat_work_group_size(256, 256), amdgpu_waves_per_eu(1, 1)))
scan_kernel(const float* __restrict__ x,
            const float* __restrict__ precp,
            const float* __restrict__ temp,
            const float* __restrict__ lday,
            const float* __restrict__ W1, const float* __restrict__ b1,
            const float* __restrict__ W2, const float* __restrict__ b2,
            const float* __restrict__ W3, const float* __restrict__ b3,
            float* __restrict__ sol, int T)
{
    const int tid  = threadIdx.x;      // 0..255
    const int lane = tid & 63;
    const int w    = tid >> 6;         // wave 0..3 (owns K-rows 32w..32w+31)
    const int kcol = (w << 5) + (lane & 31);   // layer-1 column this lane computes

    __shared__ float part[2][4][128];                  // [parity][wave][col]
    __shared__ float pr_s[CHUNK + 1], tm_s[CHUNK + 1], ld_s[CHUNK + 1];

    // ---- layer-1 weights for column kcol ----
    float w1q[4];
#pragma unroll
    for (int i = 0; i < 4; ++i) w1q[i] = W1[i * 128 + kcol];
    float b1q = b1[kcol];

    // ---- layer-2 weights: rows [32w,32w+32) of columns lane and lane+64 ----
    float w2a[32], w2b[32];
#pragma unroll
    for (int k = 0; k < 32; ++k) {
        const int row = (w << 5) + k;
        w2a[k] = W2[row * 128 + lane];
        w2b[k] = W2[row * 128 + lane + 64];
    }
    float b2a = b2[lane], b2b = b2[lane + 64];

    // ---- layer-3 weights: columns lane and lane+64 ----
    float w3a[5], w3b[5];
#pragma unroll
    for (int c = 0; c < 5; ++c) {
        w3a[c] = W3[lane * 5 + c];
        w3b[c] = W3[(lane + 64) * 5 + c];
    }
    const float b30 = b3[0], b31 = b3[1], b32 = b3[2], b33 = b3[3], b34 = b3[4];

    float S0 = x[0], S1 = x[1];
    if (tid == 0) { sol[0] = S0; sol[1] = S1; }

    auto rhs = [&](int par, float z0, float z1, float pr, float tm, float ld,
                   float& d0, float& d1) {
        // uniform transcendentals independent of the MLP — off the critical chain
        const float sS0 = step_fast(z0);
        const float sS1 = step_fast(z1);
        const float sNT = step_fast(-tm);

        // layer 1: this wave's 32 K-rows (lanes 32-63 duplicate lanes 0-31)
        float a = b1q;
        a = fmaf(z0, w1q[0], a);
        a = fmaf(z1, w1q[1], a);
        a = fmaf(pr, w1q[2], a);
        a = fmaf(tm, w1q[3], a);
        const float h = tanh_fast(a);

        // layer 2: direct readlane broadcast (VALU, no LDS); 8 accumulators
        float aa0 = 0.f, aa1 = 0.f, aa2 = 0.f, aa3 = 0.f;
        float ab0 = 0.f, ab1 = 0.f, ab2 = 0.f, ab3 = 0.f;
#pragma unroll
        for (int k = 0; k < 32; k += 4) {
            const float hk0 = readlane_f(h, k);
            const float hk1 = readlane_f(h, k + 1);
            const float hk2 = readlane_f(h, k + 2);
            const float hk3 = readlane_f(h, k + 3);
            aa0 = fmaf(hk0, w2a[k],     aa0);
            ab0 = fmaf(hk0, w2b[k],     ab0);
            aa1 = fmaf(hk1, w2a[k + 1], aa1);
            ab1 = fmaf(hk1, w2b[k + 1], ab1);
            aa2 = fmaf(hk2, w2a[k + 2], aa2);
            ab2 = fmaf(hk2, w2b[k + 2], ab2);
            aa3 = fmaf(hk3, w2a[k + 3], aa3);
            ab3 = fmaf(hk3, w2b[k + 3], ab3);
        }
        // cross-wave combine: the ONLY LDS in the rhs
        part[par][w][lane]      = (aa0 + aa1) + (aa2 + aa3);
        part[par][w][lane + 64] = (ab0 + ab1) + (ab2 + ab3);
        barrier_lgkm();                                    // the ONE barrier (lgkm only)

        const float sa = ((part[par][0][lane] + part[par][1][lane]) +
                          (part[par][2][lane] + part[par][3][lane])) + b2a;
        const float sb = ((part[par][0][lane + 64] + part[par][1][lane + 64]) +
                          (part[par][2][lane + 64] + part[par][3][lane + 64])) + b2b;
        const float h2a = tanh_fast(sa);
        const float h2b = tanh_fast(sb);

        // layer 3: per-lane partials over 2 columns -> 5 wave sums (uniform)
        const float o0 = wave_sum64(fmaf(h2b, w3b[0], h2a * w3a[0])) + b30;
        const float o1 = wave_sum64(fmaf(h2b, w3b[1], h2a * w3a[1])) + b31;
        const float o2 = wave_sum64(fmaf(h2b, w3b[2], h2a * w3a[2])) + b32;
        const float o3 = wave_sum64(fmaf(h2b, w3b[3], h2a * w3a[3])) + b33;
        const float o4 = wave_sum64(fmaf(h2b, w3b[4], h2a * w3a[4])) + b34;

        // epilogue (uniform)
        const float melt = sS0 * sinh_fast(o2);            // relu(step)=step
        d0 = fmaxf(sinh_fast(o3) * sNT, 0.0f) - melt;
        d1 = fmaxf(sinh_fast(o4), 0.0f) + melt
             - sS1 * fmaf(ld, exp_fast(o0), exp_fast(o1));
    };

    // rolling register prefetch (B of step n == A of step n+1)
    float pB = precp[0], tB = temp[0], lB = lday[0];

    for (int cbase = 0; cbase < T - 1; cbase += CHUNK) {
        for (int i = tid; i <= CHUNK; i += 256) {
            int g = cbase + i;
            if (g < T) {
                pr_s[i] = precp[g];
                tm_s[i] = temp[g];
                ld_s[i] = lday[g];
            }
        }
        __syncthreads();

        const int len = min(T - 1 - cbase, CHUNK);
#pragma unroll 1
        for (int l = 0; l < len; ++l) {
            const float pA = pB, tA = tB, lA = lB;
            pB = pr_s[l + 1];
            tB = tm_s[l + 1];
            lB = ld_s[l + 1];
            const float pM = 0.5f * (pA + pB);
            const float tM = 0.5f * (tA + tB);
            const float lM = 0.5f * (lA + lB);

            float k10, k11, k20, k21, k30, k31, k40, k41;
            rhs(0, S0, S1, pA, tA, lA, k10, k11);                              // h = 1
            rhs(1, fmaf(0.5f, k10, S0), fmaf(0.5f, k11, S1), pM, tM, lM, k20, k21);
            rhs(0, fmaf(0.5f, k20, S0), fmaf(0.5f, k21, S1), pM, tM, lM, k30, k31);
            rhs(1, k30 + S0,            k31 + S1,            pB, tB, lB, k40, k41);

            const float c = 1.0f / 6.0f;
            S0 = S0 + c * (k10 + 2.0f * (k20 + k30) + k40);
            S1 = S1 + c * (k11 + 2.0f * (k21 + k31) + k41);
            if (tid == 0) {
                const int n = cbase + l;
                sol[2 * (n + 1)]     = S0;
                sol[2 * (n + 1) + 1] = S1;
            }
        }
        __syncthreads();   // protect series LDS re-stage vs stragglers
    }
}

// ---------------------------------------------------------------------------
// Output: y[t] = exp(mlp([sol0,sol1,x2,x3])[1]) — fully parallel, tiny.
// ---------------------------------------------------------------------------
extern "C" __global__ void __launch_bounds__(128)
out_kernel(const float* __restrict__ x,
           const float* __restrict__ sol,
           const float* __restrict__ W1, const float* __restrict__ b1,
           const float* __restrict__ W2, const float* __restrict__ b2,
           const float* __restrict__ W3, const float* __restrict__ b3,
           float* __restrict__ y, int T)
{
    const int j    = threadIdx.x;
    const int lane = j & 63;
    const int wv   = j >> 6;

    __shared__ __align__(16) float h1s[128];
    __shared__ float red[2];

    float w1c[4], w2c[128];
#pragma unroll
    for (int i = 0; i < 4; ++i)   w1c[i] = W1[i * 128 + j];
    const float b1j = b1[j];
#pragma unroll
    for (int i = 0; i < 128; ++i) w2c[i] = W2[i * 128 + j];
    const float b2j = b2[j];
    const float w31 = W3[j * 5 + 1];
    const float b31 = b3[1];

#pragma unroll 1
    for (int r = blockIdx.x; r < T; r += gridDim.x) {
        const float z0 = sol[2 * r], z1 = sol[2 * r + 1];
        const float z2 = x[4 * r + 2], z3 = x[4 * r + 3];
        float a = b1j;
        a = fmaf(z0, w1c[0], a);
        a = fmaf(z1, w1c[1], a);
        a = fmaf(z2, w1c[2], a);
        a = fmaf(z3, w1c[3], a);
        h1s[j] = tanh_fast(a);
        __syncthreads();
        float acc0 = 0.f, acc1 = 0.f, acc2 = 0.f, acc3 = 0.f;
#pragma unroll
        for (int i = 0; i < 128; i += 4) {
            const float4 hv = *reinterpret_cast<const float4*>(&h1s[i]);
            acc0 = fmaf(hv.x, w2c[i + 0], acc0);
            acc1 = fmaf(hv.y, w2c[i + 1], acc1);
            acc2 = fmaf(hv.z, w2c[i + 2], acc2);
            acc3 = fmaf(hv.w, w2c[i + 3], acc3);
        }
        const float h2 = tanh_fast(((acc0 + acc1) + (acc2 + acc3)) + b2j);
        float p = h2 * w31;
#pragma unroll
        for (int off = 32; off >= 1; off >>= 1)
            p += __shfl_xor(p, off);
        if (lane == 0) red[wv] = p;
        __syncthreads();
        if (j == 0) y[r] = exp_fast(red[0] + red[1] + b31);
        __syncthreads();
    }
}

// ---------------------------------------------------------------------------
extern "C" void kernel_launch(void* const* d_in, const int* in_sizes, int n_in,
                              void* d_out, int out_size, void* d_ws, size_t ws_size,
                              hipStream_t stream)
{
    const float* x      = (const float*)d_in[0];
    // d_in[1] = t_eval = arange(T) -> h == 1.0
    // d_in[2] = t_grid = arange(T)
    const float* precp  = (const float*)d_in[3];
    const float* temp   = (const float*)d_in[4];
    const float* lday   = (const float*)d_in[5];
    const float* W1     = (const float*)d_in[6];
    const float* b1     = (const float*)d_in[7];
    const float* W2     = (const float*)d_in[8];
    const float* b2     = (const float*)d_in[9];
    const float* W3     = (const float*)d_in[10];
    const float* b3     = (const float*)d_in[11];
    float*       y      = (float*)d_out;
    float*       sol    = (float*)d_ws;      // T*2 floats
    const int    T      = in_sizes[1];

    hipLaunchKernelGGL(scan_kernel, dim3(1), dim3(256), 0, stream,
                       x, precp, temp, lday,
                       W1, b1, W2, b2, W3, b3, sol, T);
    hipLaunchKernelGGL(out_kernel, dim3(256), dim3(128), 0, stream,
                       x, sol, W1, b1, W2, b2, W3, b3, y, T);
}